// Round 3
// baseline (376.816 us; speedup 1.0000x reference)
//
#include <hip/hip_runtime.h>
#include <math.h>

#define N_ 4096
#define F_ 128
#define D_ 64
#define KH_ 3
#define ZS_ 16             // K-split for agemm (grid 16*3*16 = 768 = 3 blocks/CU)
#define KC_ (N_ / ZS_)     // 256 columns per z-slice
#define BM_ 256            // agemm row-tile

// workspace layout (float offsets) — ~9 MB total
#define OFF_E      0                          // N*D
#define OFF_XW     (N_*D_)                    // KH*N*D
#define OFF_SEP    (OFF_XW + KH_*N_*D_)       // 64*64 per-block colsum partials
#define OFF_T      (OFF_SEP + 64*64)          // KH*D*D
#define OFF_RS     (OFF_T + KH_*D_*D_)        // KH*N raw rowsums
#define OFF_DVEC   (OFF_RS + KH_*N_)          // KH*N
#define OFF_YT     (OFF_DVEC + KH_*N_)        // KH*D*N bf16
#define OFF_AY     (OFF_YT + KH_*D_*N_/2)     // KH*N*D accumulated via atomics

typedef __attribute__((ext_vector_type(8))) short bf16x8;
typedef __attribute__((ext_vector_type(4))) float f32x4;

static __device__ __forceinline__ unsigned short f2bf(float f) {
  union { float f; unsigned u; } v; v.f = f;
  unsigned r = (v.u + 0x7fffu + ((v.u >> 16) & 1u)) >> 16;
  return (unsigned short)r;
}

static __device__ __forceinline__ uint4 pack8(float4 a, float4 b) {
  union { unsigned short u[8]; uint4 q; } pk;
  pk.u[0] = f2bf(a.x); pk.u[1] = f2bf(a.y); pk.u[2] = f2bf(a.z); pk.u[3] = f2bf(a.w);
  pk.u[4] = f2bf(b.x); pk.u[5] = f2bf(b.y); pk.u[6] = f2bf(b.z); pk.u[7] = f2bf(b.w);
  return pk.q;
}

static __device__ __forceinline__ void gload_lds16(const unsigned short* g,
                                                   unsigned short* l) {
  __builtin_amdgcn_global_load_lds(
      (__attribute__((address_space(1))) unsigned int*)g,
      (__attribute__((address_space(3))) unsigned int*)l, 16, 0, 0);
}

// ---- K1 front: blocks [0,256) = proj (E, XW, SEP partials, zero T);
//                blocks [256,3328) = rowsum of A (REGULAR loads -> A stays in
//                LLC for agemm) + zero a stripe of AY.
__global__ __launch_bounds__(256) void front_kernel(
    const float* __restrict__ A, const float* __restrict__ X,
    const float* __restrict__ W_emb, const float* __restrict__ W_hops,
    float* __restrict__ ws)
{
  const int t = threadIdx.x;
  if (blockIdx.x >= 256) {
    // ---------------- rowsum role ----------------
    const int db = blockIdx.x - 256;           // 0..3071
    ws[OFF_AY + db * 256 + t] = 0.f;           // zero AY stripe (3072*256 = KH*N*D)
    int lane = t & 63;
    int wave = t >> 6;
    int row = db * 4 + wave;                   // 0..KH*N-1
    const f32x4* Ar = (const f32x4*)(A + (size_t)row * N_);
    float s = 0.f;
#pragma unroll
    for (int it = 0; it < 8; ++it) {
      f32x4 v0 = Ar[it * 128 + lane * 2 + 0];
      f32x4 v1 = Ar[it * 128 + lane * 2 + 1];
      s += (v0[0] + v0[1]) + (v0[2] + v0[3]) + (v1[0] + v1[1]) + (v1[2] + v1[3]);
    }
#pragma unroll
    for (int off = 32; off > 0; off >>= 1)
      s += __shfl_xor(s, off);
    if (lane == 0) ws[OFF_RS + row] = s;
    return;
  }
  // ---------------- proj role ----------------
  __shared__ __align__(16) float sXT[32][68];  // [f][i]
  __shared__ __align__(16) float sW[32][68];   // [f][d]
  const int m = blockIdx.x >> 6;               // 0 -> E, 1..3 -> XW[m-1]
  const int rb = blockIdx.x & 63;
  const int row0 = rb * 64;
  const float* W = (m == 0) ? W_emb : (W_hops + (size_t)(m - 1) * F_ * D_);
  float* out = (m == 0) ? (ws + OFF_E) : (ws + OFF_XW + (size_t)(m - 1) * N_ * D_);
  const int tx = t & 15, ty = t >> 4;
  const int d0 = tx * 4, i0 = ty * 4;
  float acc[4][4] = {};
  for (int fc = 0; fc < F_; fc += 32) {
    {
      int i_l = t >> 3;               // 0..31
      int f_l = (t & 7) * 4;          // 0..28
      for (int r = 0; r < 2; ++r) {
        int i = i_l + r * 32;
        float4 v = *(const float4*)(X + (size_t)(row0 + i) * F_ + fc + f_l);
        sXT[f_l + 0][i] = v.x; sXT[f_l + 1][i] = v.y;
        sXT[f_l + 2][i] = v.z; sXT[f_l + 3][i] = v.w;
      }
      int f2 = t >> 4;                // 0..15
      int d  = (t & 15) * 4;
      for (int r = 0; r < 2; ++r) {
        int f = f2 + r * 16;
        *(float4*)&sW[f][d] = *(const float4*)(W + (size_t)(fc + f) * D_ + d);
      }
    }
    __syncthreads();
#pragma unroll 8
    for (int f = 0; f < 32; ++f) {
      float a[4], b[4];
      *(float4*)a = *(const float4*)&sXT[f][i0];
      *(float4*)b = *(const float4*)&sW[f][d0];
      for (int x = 0; x < 4; ++x)
        for (int y = 0; y < 4; ++y)
          acc[x][y] += a[x] * b[y];
    }
    __syncthreads();
  }
  for (int x = 0; x < 4; ++x)
    *(float4*)(out + (size_t)(row0 + i0 + x) * D_ + d0) = *(float4*)acc[x];
  if (m == 0) {
    // per-block column-sum partials of E -> SEP[rb][0..63] (no atomics)
    float p[4];
    for (int y = 0; y < 4; ++y)
      p[y] = acc[0][y] + acc[1][y] + acc[2][y] + acc[3][y];
    *(float4*)&sXT[ty][d0] = *(float4*)p;
    __syncthreads();
    if (ty < 4) {
      int c = ty * 16 + tx;
      float s = 0.f;
#pragma unroll
      for (int r = 0; r < 16; ++r) s += sXT[r][c];
      ws[OFF_SEP + rb * 64 + c] = s;
    }
    if (rb == 0)
      for (int i = t; i < KH_ * D_ * D_; i += 256) ws[OFF_T + i] = 0.f;
  }
}

// ------- K2 prep: x<64 -> yprep; x>=64 -> tmat. dvec = rsqrt(rs + a*E.S) ----
__global__ __launch_bounds__(256) void prep_kernel(float* __restrict__ ws,
                                                   const float* __restrict__ alpha_p)
{
  const int k = blockIdx.y;
  const float* XWk = ws + OFF_XW + (size_t)k * N_ * D_;
  const float* E   = ws + OFF_E;
  const float* rs  = ws + OFF_RS + (size_t)k * N_;
  const float alpha = *alpha_p;
  int t = threadIdx.x;

  if (blockIdx.x < 64) {
    // ---------------- yprep role ----------------
    const int j0 = blockIdx.x * 64;
    unsigned short* Ytk = (unsigned short*)(ws + OFF_YT) + (size_t)k * D_ * N_;
    __shared__ float sS[64];
    __shared__ float sSp[4][64];
    __shared__ float d_l[64];
    __shared__ __align__(16) float sEy[64][65];
    __shared__ float sT[64][65];         // [n][j]
    {
      int wv = t >> 6, ln = t & 63;
      float sp = 0.f;
#pragma unroll
      for (int r = 0; r < 16; ++r) sp += ws[OFF_SEP + (wv * 16 + r) * 64 + ln];
      sSp[wv][ln] = sp;
    }
    {
      int j = t >> 2, c0 = (t & 3) * 16;
      for (int r = 0; r < 4; ++r)
        *(float4*)&sEy[j][c0 + 4 * r] = *(const float4*)(E + (size_t)(j0 + j) * D_ + c0 + 4 * r);
    }
    __syncthreads();
    if (t < 64) sS[t] = sSp[0][t] + sSp[1][t] + sSp[2][t] + sSp[3][t];
    __syncthreads();
    {
      // 4 lanes per row: dot(E_row, S)
      int j = t >> 2, c0 = (t & 3) * 16;
      float dot = 0.f;
#pragma unroll
      for (int c = 0; c < 16; ++c) dot += sEy[j][c0 + c] * sS[c0 + c];
      dot += __shfl_xor(dot, 1);
      dot += __shfl_xor(dot, 2);
      if ((t & 3) == 0) {
        float dv = 1.0f / sqrtf(rs[j0 + j] + alpha * dot);
        d_l[j] = dv;
        ws[OFF_DVEC + (size_t)k * N_ + j0 + j] = dv;
      }
    }
    __syncthreads();
    {
      int j = t >> 2;
      int c0 = (t & 3) * 16;
      float dv = d_l[j];
      for (int r = 0; r < 4; ++r) {
        float4 v = *(const float4*)(XWk + (size_t)(j0 + j) * D_ + c0 + 4 * r);
        sT[c0 + 4 * r + 0][j] = v.x * dv;
        sT[c0 + 4 * r + 1][j] = v.y * dv;
        sT[c0 + 4 * r + 2][j] = v.z * dv;
        sT[c0 + 4 * r + 3][j] = v.w * dv;
      }
    }
    __syncthreads();
    {
      int n = t >> 2;
      int jq = (t & 3) * 16;
      __align__(16) unsigned short buf[16];
#pragma unroll
      for (int i = 0; i < 16; ++i) buf[i] = f2bf(sT[n][jq + i]);
      uint4* dst = (uint4*)(Ytk + (size_t)n * N_ + j0 + jq);
      dst[0] = *(uint4*)&buf[0];
      dst[1] = *(uint4*)&buf[8];
    }
  } else {
    // ---------------- tmat role: T_k += E^T @ (d ⊙ XW_k) ----------------
    __shared__ float sS2[64];
    __shared__ float sSp2[4][64];
    __shared__ float dl2[128];
    __shared__ __align__(16) float sE[32][68];
    __shared__ __align__(16) float sY[32][68];
    int base0 = (blockIdx.x - 64) * 128;
    {
      int wv = t >> 6, ln = t & 63;
      float sp = 0.f;
#pragma unroll
      for (int r = 0; r < 16; ++r) sp += ws[OFF_SEP + (wv * 16 + r) * 64 + ln];
      sSp2[wv][ln] = sp;
    }
    __syncthreads();
    if (t < 64) sS2[t] = sSp2[0][t] + sSp2[1][t] + sSp2[2][t] + sSp2[3][t];
    __syncthreads();
    {
      // 2 lanes per row: dot(E_row, S)
      int jr2 = t >> 1, h = t & 1;
      float dot = 0.f;
#pragma unroll
      for (int c = 0; c < 32; ++c)
        dot += E[(size_t)(base0 + jr2) * D_ + h * 32 + c] * sS2[h * 32 + c];
      dot += __shfl_xor(dot, 1);
      if (h == 0) dl2[jr2] = 1.0f / sqrtf(rs[base0 + jr2] + alpha * dot);
    }
    __syncthreads();
    int tx = t & 15, ty = t >> 4;
    int d0 = tx * 4, c0 = ty * 4;
    float acc[4][4] = {};
    for (int sub = 0; sub < 4; ++sub) {
      int base = base0 + sub * 32;
      {
        int i_l = t >> 3;
        int c   = (t & 7) * 4;
        float dv = dl2[sub * 32 + i_l];
        for (int r = 0; r < 2; ++r) {
          int col = c + r * 32;
          *(float4*)&sE[i_l][col] = *(const float4*)(E + (size_t)(base + i_l) * D_ + col);
          float4 y = *(const float4*)(XWk + (size_t)(base + i_l) * D_ + col);
          y.x *= dv; y.y *= dv; y.z *= dv; y.w *= dv;
          *(float4*)&sY[i_l][col] = y;
        }
      }
      __syncthreads();
#pragma unroll 8
      for (int i = 0; i < 32; ++i) {
        float c4[4], y4[4];
        *(float4*)c4 = *(const float4*)&sE[i][c0];
        *(float4*)y4 = *(const float4*)&sY[i][d0];
        for (int a = 0; a < 4; ++a)
          for (int b = 0; b < 4; ++b)
            acc[a][b] += c4[a] * y4[b];
      }
      __syncthreads();
    }
    float* Tk = ws + OFF_T + (size_t)k * D_ * D_;
    for (int a = 0; a < 4; ++a)
      for (int b = 0; b < 4; ++b)
        atomicAdd(&Tk[(c0 + a) * D_ + d0 + b], acc[a][b]);
  }
}

// ---- K3 agemm: AY[k] += A_k[:,kz] @ Y_k[kz]. A read fp32 (LLC-resident from
//      K1), converted to bf16 in reg-staging with XOR-swizzled ds_writes.
//      Y staged via global_load_lds (already bf16). Output: atomicAdd into AY.
__global__ __launch_bounds__(256, 3) void agemm_kernel(
    const float* __restrict__ A, const float* __restrict__ ws,
    float* __restrict__ AY)
{
  const int k = blockIdx.y;
  const int row0 = blockIdx.x * BM_;
  const int kz0 = blockIdx.z * KC_;
  const float* Ak = A + ((size_t)k << 24);
  const unsigned short* Ytk = (const unsigned short*)(ws + OFF_YT) + (size_t)k * D_ * N_;

  __shared__ __align__(16) unsigned short sA[BM_ * 64];  // 32 KB
  __shared__ __align__(16) unsigned short sY[64 * 64];   // 8 KB

  const int t = threadIdx.x;
  const int lane = t & 63;
  const int w = t >> 6;                // wave 0..3 -> rows w*64..w*64+63
  const int m = lane & 15;
  const int q = lane >> 4;
  const int sr = t >> 3;               // Y staging row
  const int sc = t & 7;                // Y staging chunk
  const int ar = t >> 2;               // A staging row within 64-row group
  const int ac = t & 3;                // A staging col quarter (16 floats)

  f32x4 acc[4][4];
#pragma unroll
  for (int a = 0; a < 4; ++a)
#pragma unroll
    for (int b = 0; b < 4; ++b) acc[a][b] = (f32x4){0.f, 0.f, 0.f, 0.f};

  for (int kt = 0; kt < KC_; kt += 64) {
    // Y tile via DMA (bf16 already)
#pragma unroll
    for (int j = 0; j < 2; ++j) {
      int r = j * 32 + sr;
      gload_lds16(Ytk + (size_t)r * N_ + (kz0 + kt) + ((sc ^ (r & 7)) << 3),
                  &sY[j * 2048 + t * 8]);
    }
    // A tile: fp32 LLC reads -> bf16 -> swizzled ds_write
#pragma unroll
    for (int p = 0; p < 4; ++p) {
      int r = p * 64 + ar;
      const float* g = Ak + (size_t)(row0 + r) * N_ + (kz0 + kt) + ac * 16;
      float4 v0 = *(const float4*)(g + 0);
      float4 v1 = *(const float4*)(g + 4);
      float4 v2 = *(const float4*)(g + 8);
      float4 v3 = *(const float4*)(g + 12);
      int ch0 = 2 * ac, ch1 = ch0 + 1;
      *(uint4*)&sA[r * 64 + ((ch0 ^ (r & 7)) << 3)] = pack8(v0, v1);
      *(uint4*)&sA[r * 64 + ((ch1 ^ (r & 7)) << 3)] = pack8(v2, v3);
    }
    __syncthreads();
#pragma unroll
    for (int s = 0; s < 2; ++s) {
      bf16x8 av[4], bv[4];
#pragma unroll
      for (int mr = 0; mr < 4; ++mr) {
        int row = w * 64 + mr * 16 + m;
        av[mr] = *(const bf16x8*)&sA[row * 64 + (((s * 4 + q) ^ (row & 7)) << 3)];
      }
#pragma unroll
      for (int nt = 0; nt < 4; ++nt) {
        int n = nt * 16 + m;
        bv[nt] = *(const bf16x8*)&sY[n * 64 + (((s * 4 + q) ^ (n & 7)) << 3)];
      }
#pragma unroll
      for (int mr = 0; mr < 4; ++mr)
#pragma unroll
        for (int nt = 0; nt < 4; ++nt)
          acc[mr][nt] = __builtin_amdgcn_mfma_f32_16x16x32_bf16(av[mr], bv[nt],
                                                                acc[mr][nt], 0, 0, 0);
    }
    __syncthreads();
  }
  // C/D layout: col = lane&15, row = q*4 + reg; accumulate across z via atomics
#pragma unroll
  for (int mr = 0; mr < 4; ++mr) {
    float* outp = AY + ((size_t)k * N_ + row0 + w * 64 + mr * 16) * D_;
#pragma unroll
    for (int nt = 0; nt < 4; ++nt)
#pragma unroll
      for (int r = 0; r < 4; ++r)
        atomicAdd(&outp[(size_t)(q * 4 + r) * D_ + nt * 16 + m], acc[mr][nt][r]);
  }
}

// ---- K4 epilogue: out = relu(sum_k d_i*(AY_k + alpha*E@T_k)) ---------------
__global__ __launch_bounds__(256) void epilogue_kernel(
    const float* __restrict__ ws, const float* __restrict__ alpha_p,
    float* __restrict__ out)
{
  int g = blockIdx.x * 256 + threadIdx.x;
  int i = g >> 6, d = g & 63;
  const float* E = ws + OFF_E;
  float alpha = *alpha_p;
  float s = 0.f;
#pragma unroll
  for (int k = 0; k < KH_; ++k) {
    float ay = ws[OFF_AY + ((size_t)k * N_ + i) * D_ + d];
    float lr = 0.f;
    const float* Tk = ws + OFF_T + k * D_ * D_;
#pragma unroll 16
    for (int c = 0; c < D_; ++c)
      lr += E[(size_t)i * D_ + c] * Tk[c * D_ + d];
    s += ws[OFF_DVEC + k * N_ + i] * (ay + alpha * lr);
  }
  out[g] = fmaxf(s, 0.f);
}

extern "C" void kernel_launch(void* const* d_in, const int* in_sizes, int n_in,
                              void* d_out, int out_size, void* d_ws, size_t ws_size,
                              hipStream_t stream) {
  const float* X      = (const float*)d_in[0];
  const float* A      = (const float*)d_in[1];
  const float* W_emb  = (const float*)d_in[2];
  const float* W_hops = (const float*)d_in[3];
  const float* alpha_p= (const float*)d_in[4];
  float* out = (float*)d_out;
  float* ws  = (float*)d_ws;

  front_kernel<<<dim3(256 + KH_ * N_ / 4), 256, 0, stream>>>(A, X, W_emb, W_hops, ws);
  prep_kernel<<<dim3(96, KH_), 256, 0, stream>>>(ws, alpha_p);
  agemm_kernel<<<dim3(N_ / BM_, KH_, ZS_), 256, 0, stream>>>(A, ws, ws + OFF_AY);
  epilogue_kernel<<<dim3(N_ * D_ / 256), 256, 0, stream>>>(ws, alpha_p, out);
}

// Round 4
// 336.402 us; speedup vs baseline: 1.1201x; 1.1201x over previous
//
#include <hip/hip_runtime.h>
#include <math.h>

#define N_ 4096
#define F_ 128
#define D_ 64
#define KH_ 3
#define ZS_ 8              // K-split for agemm
#define KC_ (N_ / ZS_)     // 512 columns per z-slice
#define BM_ 128            // agemm row-tile (grid 32*3*8 = 768 = 3 blocks/CU)

// workspace layout (float offsets) — ~132 MB total
#define OFF_E      0                          // N*D
#define OFF_XW     (N_*D_)                    // KH*N*D
#define OFF_SEP    (OFF_XW + KH_*N_*D_)       // 64*64 per-block colsum partials
#define OFF_T      (OFF_SEP + 64*64)          // KH*D*D
#define OFF_RS     (OFF_T + KH_*D_*D_)        // KH*N raw rowsums
#define OFF_DVEC   (OFF_RS + KH_*N_)          // KH*N
#define OFF_YT     (OFF_DVEC + KH_*N_)        // KH*D*N bf16
#define OFF_AYP    (OFF_YT + KH_*D_*N_/2)     // ZS*KH*N*D
#define OFF_ABF    (OFF_AYP + ZS_*KH_*N_*D_)  // KH*N*N bf16

typedef __attribute__((ext_vector_type(8))) short bf16x8;
typedef __attribute__((ext_vector_type(4))) float f32x4;

static __device__ __forceinline__ unsigned short f2bf(float f) {
  union { float f; unsigned u; } v; v.f = f;
  unsigned r = (v.u + 0x7fffu + ((v.u >> 16) & 1u)) >> 16;
  return (unsigned short)r;
}

static __device__ __forceinline__ uint4 pack8v(f32x4 a, f32x4 b) {
  union { unsigned short u[8]; uint4 q; } pk;
  pk.u[0] = f2bf(a[0]); pk.u[1] = f2bf(a[1]); pk.u[2] = f2bf(a[2]); pk.u[3] = f2bf(a[3]);
  pk.u[4] = f2bf(b[0]); pk.u[5] = f2bf(b[1]); pk.u[6] = f2bf(b[2]); pk.u[7] = f2bf(b[3]);
  return pk.q;
}

static __device__ __forceinline__ void gload_lds16(const unsigned short* g,
                                                   unsigned short* l) {
  __builtin_amdgcn_global_load_lds(
      (__attribute__((address_space(1))) unsigned int*)g,
      (__attribute__((address_space(3))) unsigned int*)l, 16, 0, 0);
}

// ---- K1 front: blocks [0,256) = proj (E, XW, SEP partials, zero T);
//      blocks [256,3328) = degconv: rowsum of A (NONTEMPORAL fp32 loads — A is
//      dead after this pass, keeps LLC free for Abf) + Abf = bf16(A).
__global__ __launch_bounds__(256) void front_kernel(
    const float* __restrict__ A, const float* __restrict__ X,
    const float* __restrict__ W_emb, const float* __restrict__ W_hops,
    float* __restrict__ ws)
{
  const int t = threadIdx.x;
  if (blockIdx.x >= 256) {
    // ---------------- degconv role ----------------
    const int db = blockIdx.x - 256;           // 0..3071
    int lane = t & 63;
    int wave = t >> 6;
    int row = db * 4 + wave;                   // 0..KH*N-1
    const f32x4* Ar = (const f32x4*)(A + (size_t)row * N_);
    unsigned short* Br = (unsigned short*)(ws + OFF_ABF) + (size_t)row * N_;
    float s = 0.f;
#pragma unroll
    for (int it = 0; it < 8; ++it) {
      f32x4 v0 = __builtin_nontemporal_load(Ar + it * 128 + lane * 2 + 0);
      f32x4 v1 = __builtin_nontemporal_load(Ar + it * 128 + lane * 2 + 1);
      s += (v0[0] + v0[1]) + (v0[2] + v0[3]) + (v1[0] + v1[1]) + (v1[2] + v1[3]);
      *(uint4*)(Br + (size_t)it * 512 + lane * 8) = pack8v(v0, v1);
    }
#pragma unroll
    for (int off = 32; off > 0; off >>= 1)
      s += __shfl_xor(s, off);
    if (lane == 0) ws[OFF_RS + row] = s;
    return;
  }
  // ---------------- proj role ----------------
  __shared__ __align__(16) float sXT[32][68];  // [f][i]
  __shared__ __align__(16) float sW[32][68];   // [f][d]
  const int m = blockIdx.x >> 6;               // 0 -> E, 1..3 -> XW[m-1]
  const int rb = blockIdx.x & 63;
  const int row0 = rb * 64;
  const float* W = (m == 0) ? W_emb : (W_hops + (size_t)(m - 1) * F_ * D_);
  float* out = (m == 0) ? (ws + OFF_E) : (ws + OFF_XW + (size_t)(m - 1) * N_ * D_);
  const int tx = t & 15, ty = t >> 4;
  const int d0 = tx * 4, i0 = ty * 4;
  float acc[4][4] = {};
  for (int fc = 0; fc < F_; fc += 32) {
    {
      int i_l = t >> 3;               // 0..31
      int f_l = (t & 7) * 4;          // 0..28
      for (int r = 0; r < 2; ++r) {
        int i = i_l + r * 32;
        float4 v = *(const float4*)(X + (size_t)(row0 + i) * F_ + fc + f_l);
        sXT[f_l + 0][i] = v.x; sXT[f_l + 1][i] = v.y;
        sXT[f_l + 2][i] = v.z; sXT[f_l + 3][i] = v.w;
      }
      int f2 = t >> 4;                // 0..15
      int d  = (t & 15) * 4;
      for (int r = 0; r < 2; ++r) {
        int f = f2 + r * 16;
        *(float4*)&sW[f][d] = *(const float4*)(W + (size_t)(fc + f) * D_ + d);
      }
    }
    __syncthreads();
#pragma unroll 8
    for (int f = 0; f < 32; ++f) {
      float a[4], b[4];
      *(float4*)a = *(const float4*)&sXT[f][i0];
      *(float4*)b = *(const float4*)&sW[f][d0];
      for (int x = 0; x < 4; ++x)
        for (int y = 0; y < 4; ++y)
          acc[x][y] += a[x] * b[y];
    }
    __syncthreads();
  }
  for (int x = 0; x < 4; ++x)
    *(float4*)(out + (size_t)(row0 + i0 + x) * D_ + d0) = *(float4*)acc[x];
  if (m == 0) {
    // per-block column-sum partials of E -> SEP[rb][0..63] (no atomics)
    float p[4];
    for (int y = 0; y < 4; ++y)
      p[y] = acc[0][y] + acc[1][y] + acc[2][y] + acc[3][y];
    *(float4*)&sXT[ty][d0] = *(float4*)p;
    __syncthreads();
    if (ty < 4) {
      int c = ty * 16 + tx;
      float s = 0.f;
#pragma unroll
      for (int r = 0; r < 16; ++r) s += sXT[r][c];
      ws[OFF_SEP + rb * 64 + c] = s;
    }
    if (rb == 0)
      for (int i = t; i < KH_ * D_ * D_; i += 256) ws[OFF_T + i] = 0.f;
  }
}

// ------- K2 prep: x<64 -> yprep; x>=64 -> tmat. dvec = rsqrt(rs + a*E.S) ----
__global__ __launch_bounds__(256) void prep_kernel(float* __restrict__ ws,
                                                   const float* __restrict__ alpha_p)
{
  const int k = blockIdx.y;
  const float* XWk = ws + OFF_XW + (size_t)k * N_ * D_;
  const float* E   = ws + OFF_E;
  const float* rs  = ws + OFF_RS + (size_t)k * N_;
  const float alpha = *alpha_p;
  int t = threadIdx.x;

  if (blockIdx.x < 64) {
    // ---------------- yprep role ----------------
    const int j0 = blockIdx.x * 64;
    unsigned short* Ytk = (unsigned short*)(ws + OFF_YT) + (size_t)k * D_ * N_;
    __shared__ float sS[64];
    __shared__ float sSp[4][64];
    __shared__ float d_l[64];
    __shared__ __align__(16) float sEy[64][65];
    __shared__ float sT[64][65];         // [n][j]
    {
      int wv = t >> 6, ln = t & 63;
      float sp = 0.f;
#pragma unroll
      for (int r = 0; r < 16; ++r) sp += ws[OFF_SEP + (wv * 16 + r) * 64 + ln];
      sSp[wv][ln] = sp;
    }
    {
      int j = t >> 2, c0 = (t & 3) * 16;
      for (int r = 0; r < 4; ++r)
        *(float4*)&sEy[j][c0 + 4 * r] = *(const float4*)(E + (size_t)(j0 + j) * D_ + c0 + 4 * r);
    }
    __syncthreads();
    if (t < 64) sS[t] = sSp[0][t] + sSp[1][t] + sSp[2][t] + sSp[3][t];
    __syncthreads();
    {
      int j = t >> 2, c0 = (t & 3) * 16;
      float dot = 0.f;
#pragma unroll
      for (int c = 0; c < 16; ++c) dot += sEy[j][c0 + c] * sS[c0 + c];
      dot += __shfl_xor(dot, 1);
      dot += __shfl_xor(dot, 2);
      if ((t & 3) == 0) {
        float dv = 1.0f / sqrtf(rs[j0 + j] + alpha * dot);
        d_l[j] = dv;
        ws[OFF_DVEC + (size_t)k * N_ + j0 + j] = dv;
      }
    }
    __syncthreads();
    {
      int j = t >> 2;
      int c0 = (t & 3) * 16;
      float dv = d_l[j];
      for (int r = 0; r < 4; ++r) {
        float4 v = *(const float4*)(XWk + (size_t)(j0 + j) * D_ + c0 + 4 * r);
        sT[c0 + 4 * r + 0][j] = v.x * dv;
        sT[c0 + 4 * r + 1][j] = v.y * dv;
        sT[c0 + 4 * r + 2][j] = v.z * dv;
        sT[c0 + 4 * r + 3][j] = v.w * dv;
      }
    }
    __syncthreads();
    {
      int n = t >> 2;
      int jq = (t & 3) * 16;
      __align__(16) unsigned short buf[16];
#pragma unroll
      for (int i = 0; i < 16; ++i) buf[i] = f2bf(sT[n][jq + i]);
      uint4* dst = (uint4*)(Ytk + (size_t)n * N_ + j0 + jq);
      dst[0] = *(uint4*)&buf[0];
      dst[1] = *(uint4*)&buf[8];
    }
  } else {
    // ---------------- tmat role: T_k += E^T @ (d ⊙ XW_k) ----------------
    __shared__ float sS2[64];
    __shared__ float sSp2[4][64];
    __shared__ float dl2[128];
    __shared__ __align__(16) float sE[32][68];
    __shared__ __align__(16) float sY[32][68];
    int base0 = (blockIdx.x - 64) * 128;
    {
      int wv = t >> 6, ln = t & 63;
      float sp = 0.f;
#pragma unroll
      for (int r = 0; r < 16; ++r) sp += ws[OFF_SEP + (wv * 16 + r) * 64 + ln];
      sSp2[wv][ln] = sp;
    }
    __syncthreads();
    if (t < 64) sS2[t] = sSp2[0][t] + sSp2[1][t] + sSp2[2][t] + sSp2[3][t];
    __syncthreads();
    {
      int jr2 = t >> 1, h = t & 1;
      float dot = 0.f;
#pragma unroll
      for (int c = 0; c < 32; ++c)
        dot += E[(size_t)(base0 + jr2) * D_ + h * 32 + c] * sS2[h * 32 + c];
      dot += __shfl_xor(dot, 1);
      if (h == 0) dl2[jr2] = 1.0f / sqrtf(rs[base0 + jr2] + alpha * dot);
    }
    __syncthreads();
    int tx = t & 15, ty = t >> 4;
    int d0 = tx * 4, c0 = ty * 4;
    float acc[4][4] = {};
    for (int sub = 0; sub < 4; ++sub) {
      int base = base0 + sub * 32;
      {
        int i_l = t >> 3;
        int c   = (t & 7) * 4;
        float dv = dl2[sub * 32 + i_l];
        for (int r = 0; r < 2; ++r) {
          int col = c + r * 32;
          *(float4*)&sE[i_l][col] = *(const float4*)(E + (size_t)(base + i_l) * D_ + col);
          float4 y = *(const float4*)(XWk + (size_t)(base + i_l) * D_ + col);
          y.x *= dv; y.y *= dv; y.z *= dv; y.w *= dv;
          *(float4*)&sY[i_l][col] = y;
        }
      }
      __syncthreads();
#pragma unroll 8
      for (int i = 0; i < 32; ++i) {
        float c4[4], y4[4];
        *(float4*)c4 = *(const float4*)&sE[i][c0];
        *(float4*)y4 = *(const float4*)&sY[i][d0];
        for (int a = 0; a < 4; ++a)
          for (int b = 0; b < 4; ++b)
            acc[a][b] += c4[a] * y4[b];
      }
      __syncthreads();
    }
    float* Tk = ws + OFF_T + (size_t)k * D_ * D_;
    for (int a = 0; a < 4; ++a)
      for (int b = 0; b < 4; ++b)
        atomicAdd(&Tk[(c0 + a) * D_ + d0 + b], acc[a][b]);
  }
}

// ---- K3 agemm (MFMA bf16, DMA-staged): AYp[z][k] = Abf_k[:,kz] @ Y_k[kz] ----
// BM=128, each wave owns a 32x64 output tile. LDS linear (global_load_lds
// requirement); bank spread via chunk ^= row&7 on BOTH source and ds_read.
__global__ __launch_bounds__(256, 3) void agemm_kernel(
    const float* __restrict__ ws, float* __restrict__ AYp)
{
  const int k = blockIdx.y;
  const int row0 = blockIdx.x * BM_;
  const int kz0 = blockIdx.z * KC_;
  const unsigned short* Ak = (const unsigned short*)(ws + OFF_ABF) + ((size_t)k << 24);
  const unsigned short* Ytk = (const unsigned short*)(ws + OFF_YT) + (size_t)k * D_ * N_;

  __shared__ __align__(16) unsigned short sA[BM_ * 64];  // 16 KB, linear
  __shared__ __align__(16) unsigned short sY[64 * 64];   // 8 KB, linear

  const int t = threadIdx.x;
  const int lane = t & 63;
  const int w = t >> 6;                // wave 0..3 -> rows w*32..w*32+31
  const int m = lane & 15;
  const int q = lane >> 4;
  const int sr = t >> 3;               // staging row within 32-row group
  const int sc = t & 7;                // staging chunk 0..7 (16B units)

  f32x4 acc[2][4];
#pragma unroll
  for (int a = 0; a < 2; ++a)
#pragma unroll
    for (int b = 0; b < 4; ++b) acc[a][b] = (f32x4){0.f, 0.f, 0.f, 0.f};

  for (int kt = 0; kt < KC_; kt += 64) {
    // stage A: 128 rows x 64 k bf16 = 16 KB, 4 DMA issues
#pragma unroll
    for (int j = 0; j < 4; ++j) {
      int r = j * 32 + sr;
      gload_lds16(Ak + (size_t)(row0 + r) * N_ + (kz0 + kt) + ((sc ^ (r & 7)) << 3),
                  &sA[j * 2048 + t * 8]);
    }
    // stage Y: 64 n x 64 k bf16 = 8 KB, 2 DMA issues
#pragma unroll
    for (int j = 0; j < 2; ++j) {
      int r = j * 32 + sr;
      gload_lds16(Ytk + (size_t)r * N_ + (kz0 + kt) + ((sc ^ (r & 7)) << 3),
                  &sY[j * 2048 + t * 8]);
    }
    __syncthreads();
#pragma unroll
    for (int s = 0; s < 2; ++s) {
      bf16x8 av[2], bv[4];
#pragma unroll
      for (int mr = 0; mr < 2; ++mr) {
        int row = w * 32 + mr * 16 + m;
        av[mr] = *(const bf16x8*)&sA[row * 64 + (((s * 4 + q) ^ (row & 7)) << 3)];
      }
#pragma unroll
      for (int nt = 0; nt < 4; ++nt) {
        int n = nt * 16 + m;
        bv[nt] = *(const bf16x8*)&sY[n * 64 + (((s * 4 + q) ^ (n & 7)) << 3)];
      }
#pragma unroll
      for (int mr = 0; mr < 2; ++mr)
#pragma unroll
        for (int nt = 0; nt < 4; ++nt)
          acc[mr][nt] = __builtin_amdgcn_mfma_f32_16x16x32_bf16(av[mr], bv[nt],
                                                                acc[mr][nt], 0, 0, 0);
    }
    __syncthreads();
  }
  // C/D layout: col = lane&15, row = q*4 + reg
#pragma unroll
  for (int mr = 0; mr < 2; ++mr) {
    float* outp = AYp + (((size_t)blockIdx.z * KH_ + k) * N_ + row0 + w * 32 + mr * 16) * D_;
#pragma unroll
    for (int nt = 0; nt < 4; ++nt)
#pragma unroll
      for (int r = 0; r < 4; ++r)
        outp[(size_t)(q * 4 + r) * D_ + nt * 16 + m] = acc[mr][nt][r];
  }
}

// ---- K4 epilogue: out = relu(sum_k d_i*(sum_z AYp + alpha*E@T_k)) ----------
__global__ __launch_bounds__(256) void epilogue_kernel(
    const float* __restrict__ ws, const float* __restrict__ alpha_p,
    float* __restrict__ out)
{
  int g = blockIdx.x * 256 + threadIdx.x;
  int i = g >> 6, d = g & 63;
  const float* E = ws + OFF_E;
  float alpha = *alpha_p;
  float s = 0.f;
#pragma unroll
  for (int k = 0; k < KH_; ++k) {
    float ay = 0.f;
#pragma unroll
    for (int jc = 0; jc < ZS_; ++jc)
      ay += ws[OFF_AYP + (((size_t)jc * KH_ + k) * N_ + i) * D_ + d];
    float lr = 0.f;
    const float* Tk = ws + OFF_T + k * D_ * D_;
#pragma unroll 16
    for (int c = 0; c < D_; ++c)
      lr += E[(size_t)i * D_ + c] * Tk[c * D_ + d];
    s += ws[OFF_DVEC + k * N_ + i] * (ay + alpha * lr);
  }
  out[g] = fmaxf(s, 0.f);
}

extern "C" void kernel_launch(void* const* d_in, const int* in_sizes, int n_in,
                              void* d_out, int out_size, void* d_ws, size_t ws_size,
                              hipStream_t stream) {
  const float* X      = (const float*)d_in[0];
  const float* A      = (const float*)d_in[1];
  const float* W_emb  = (const float*)d_in[2];
  const float* W_hops = (const float*)d_in[3];
  const float* alpha_p= (const float*)d_in[4];
  float* out = (float*)d_out;
  float* ws  = (float*)d_ws;

  front_kernel<<<dim3(256 + KH_ * N_ / 4), 256, 0, stream>>>(A, X, W_emb, W_hops, ws);
  prep_kernel<<<dim3(96, KH_), 256, 0, stream>>>(ws, alpha_p);
  agemm_kernel<<<dim3(N_ / BM_, KH_, ZS_), 256, 0, stream>>>(ws, ws + OFF_AYP);
  epilogue_kernel<<<dim3(N_ * D_ / 256), 256, 0, stream>>>(ws, alpha_p, out);
}